// Round 5
// baseline (1738.104 us; speedup 1.0000x reference)
//
#include <hip/hip_runtime.h>
#include <cstdint>

#define DI __device__ __forceinline__

typedef __attribute__((ext_vector_type(8))) short s8v;     // 8 bf16 = 4 VGPRs
typedef __attribute__((ext_vector_type(4))) float f4v;     // MFMA acc
typedef __attribute__((ext_vector_type(4))) uint32_t u4v;  // 4 VGPRs

// ---------- helpers ----------
DI float sigmoidf_(float x) {
    return __builtin_amdgcn_rcpf(1.f + __expf(-x));
}
DI float tanhf_(float x) {
    return fmaf(-2.f, __builtin_amdgcn_rcpf(1.f + __expf(2.f * x)), 1.f);
}
DI uint32_t f2bf(float f) {
    uint32_t u = __float_as_uint(f);
    return (u + 0x7fffu + ((u >> 16) & 1u)) >> 16;
}
DI float bflo(uint32_t u) { return __uint_as_float(u << 16); }
DI float bfhi(uint32_t u) { return __uint_as_float(u & 0xffff0000u); }

// ---------- prep: weight transposes / packs ----------
// tasks: wihT [2][192][768] (294912) | wfrag u32 [2][12][4][6][64][4] (147456)
//      | bsum [2][768] (1536) | wsdT [24][48][96] (110592)
__global__ __launch_bounds__(256) void k_prep(
    const float* wihf, const float* wihb, const float* whhf, const float* whhb,
    const float* bihf, const float* bhhf, const float* bihb, const float* bhhb,
    const float* sdw,
    float* wihT, uint32_t* wfrag, float* bsum, float* wsdT)
{
    int i = blockIdx.x * 256 + threadIdx.x;
    if (i < 294912) {
        int d = i / 147456, r = i % 147456;
        int ii = r / 768, g = r % 768;
        const float* w = d ? wihb : wihf;
        wihT[i] = w[g * 192 + ii];
        return;
    }
    int j = i - 294912;
    if (j < 147456) {
        // B-fragment pack for MFMA 16x16x32 bf16: B[k][n], n=lane&15, k=(lane>>4)*8+jj
        int d = j / 73728, r = j % 73728;
        int w = r / 6144, r2 = r % 6144;
        int tau = r2 / 1536, r3 = r2 % 1536;
        int kt = r3 / 256, r4 = r3 % 256;
        int lane = r4 / 4, jp = r4 % 4;
        int n = 16 * (w + 12 * tau) + (lane & 15);
        int k0 = kt * 32 + (lane >> 4) * 8 + jp * 2;
        const float* whh = d ? whhb : whhf;   // w_hh[n][k] row-major (4H8 x H8)
        uint32_t lo = f2bf(whh[n * 192 + k0]);
        uint32_t hi = f2bf(whh[n * 192 + k0 + 1]);
        wfrag[j] = lo | (hi << 16);
        return;
    }
    int k = j - 147456;
    if (k < 1536) {
        int d = k / 768, g = k % 768;
        bsum[k] = d ? (bihb[g] + bhhb[g]) : (bihf[g] + bhhf[g]);
        return;
    }
    int l = k - 1536;
    if (l < 110592) {
        int h = l / 4608, rem = l % 4608;
        int co = rem / 96, ci = rem % 96;
        wsdT[l] = sdw[(ci * 48 + co) * 24 + h];
    }
}

// ---------- K1: sconv (24->48 over H) + bn1 + prelu ----------
__global__ __launch_bounds__(256) void k_sconv(
    const float* __restrict__ x, const float* __restrict__ w, const float* __restrict__ bias,
    const float* g, const float* bb, const float* m, const float* v, const float* a,
    float* __restrict__ x1)
{
    int t = blockIdx.x * 256 + threadIdx.x;
    int co = blockIdx.y;
    int b = blockIdx.z;
    const float* xb = x + (size_t)b * 24 * 1024 + t;
    float acc = bias[co];
#pragma unroll
    for (int h = 0; h < 24; ++h) acc = fmaf(xb[h * 1024], w[co * 24 + h], acc);
    float sc = g[co] * rsqrtf(v[co] + 1e-5f);
    float y = (acc - m[co]) * sc + bb[co];
    float al = a[0];
    y = y >= 0.f ? y : al * y;
    x1[((size_t)b * 48 + co) * 1024 + t] = y;
}

// ---------- K2/K3: strided conv (stride 2, k=16, pad 7) + bn + prelu ----------
template<int CI, int CO, int WOUT, int BSTR>
__global__ __launch_bounds__(256) void k_tconv(
    const float* __restrict__ xin, const float* __restrict__ w, const float* __restrict__ bias,
    const float* g, const float* bb, const float* m, const float* v, const float* a,
    float* __restrict__ out)
{
    const int WIN = WOUT * 2;
    __shared__ float XL[CI][144];
    int tid = threadIdx.x;
    int w0 = blockIdx.x * 64;
    int b = blockIdx.z;
    for (int idx = tid; idx < CI * 144; idx += 256) {
        int ci = idx / 144, p = idx % 144;
        int gp = 2 * w0 - 7 + p;
        XL[ci][p] = (gp >= 0 && gp < WIN) ? xin[((size_t)b * CI + ci) * WIN + gp] : 0.f;
    }
    __syncthreads();
    int tw = tid & 63, cg = tid >> 6;
    int co0 = blockIdx.y * 16 + cg * 4;
    co0 = __builtin_amdgcn_readfirstlane(co0);
    const float* wb = w + (size_t)co0 * CI * 16;
    float acc[4] = {bias[co0], bias[co0 + 1], bias[co0 + 2], bias[co0 + 3]};
    for (int ci = 0; ci < CI; ++ci) {
#pragma unroll
        for (int k = 0; k < 16; ++k) {
            float xv = XL[ci][2 * tw + k];
            acc[0] = fmaf(xv, wb[(0 * CI + ci) * 16 + k], acc[0]);
            acc[1] = fmaf(xv, wb[(1 * CI + ci) * 16 + k], acc[1]);
            acc[2] = fmaf(xv, wb[(2 * CI + ci) * 16 + k], acc[2]);
            acc[3] = fmaf(xv, wb[(3 * CI + ci) * 16 + k], acc[3]);
        }
    }
    float al = a[0];
#pragma unroll
    for (int r = 0; r < 4; ++r) {
        int co = co0 + r;
        float sc = g[co] * rsqrtf(v[co] + 1e-5f);
        float y = (acc[r] - m[co]) * sc + bb[co];
        y = y >= 0.f ? y : al * y;
        out[((size_t)b * BSTR + co) * WOUT + w0 + tw] = y;
    }
}

// ---------- x3s build: [t*32+b][192] from e0[b][192+i][t] ----------
__global__ __launch_bounds__(256) void k_x3s(const float* __restrict__ e0, float* __restrict__ x3s)
{
    __shared__ float tl[64 * 193];
    int t0 = blockIdx.x * 64, b = blockIdx.y;
    int tid = threadIdx.x;
    for (int idx = tid; idx < 192 * 64; idx += 256) {
        int i = idx >> 6, tt = idx & 63;
        tl[tt * 193 + i] = e0[((size_t)b * 384 + 192 + i) * 256 + t0 + tt];
    }
    __syncthreads();
    for (int idx = tid; idx < 64 * 192; idx += 256) {
        int tt = idx / 192, ii = idx % 192;
        x3s[((size_t)(t0 + tt) * 32 + b) * 192 + ii] = tl[tt * 193 + ii];
    }
}

// ---------- tiled GEMM: C[8192x768] = A[8192x192] * B[192x768] + bias[768] ----------
__global__ __launch_bounds__(256) void k_gemm(
    const float* __restrict__ A, const float* __restrict__ Bm,
    const float* __restrict__ bias, float* __restrict__ C)
{
    __shared__ float AL[64 * 17];
    __shared__ float BL[16 * 68];
    int tid = threadIdx.x;
    int n0 = blockIdx.x * 64, m0 = blockIdx.y * 64;
    int tx = tid & 15, ty = tid >> 4;
    float4 cc[4] = {};
    for (int k0 = 0; k0 < 192; k0 += 16) {
        for (int idx = tid; idx < 1024; idx += 256) {
            int r = idx >> 4, c = idx & 15;
            AL[r * 17 + c] = A[(size_t)(m0 + r) * 192 + k0 + c];
        }
        for (int idx = tid; idx < 1024; idx += 256) {
            int kk = idx >> 6, jj = idx & 63;
            BL[kk * 68 + jj] = Bm[(size_t)(k0 + kk) * 768 + n0 + jj];
        }
        __syncthreads();
#pragma unroll
        for (int kk = 0; kk < 16; ++kk) {
            float4 b4 = *(const float4*)&BL[kk * 68 + tx * 4];
            float a0 = AL[(ty * 4 + 0) * 17 + kk];
            float a1 = AL[(ty * 4 + 1) * 17 + kk];
            float a2 = AL[(ty * 4 + 2) * 17 + kk];
            float a3 = AL[(ty * 4 + 3) * 17 + kk];
            cc[0].x = fmaf(a0, b4.x, cc[0].x); cc[0].y = fmaf(a0, b4.y, cc[0].y);
            cc[0].z = fmaf(a0, b4.z, cc[0].z); cc[0].w = fmaf(a0, b4.w, cc[0].w);
            cc[1].x = fmaf(a1, b4.x, cc[1].x); cc[1].y = fmaf(a1, b4.y, cc[1].y);
            cc[1].z = fmaf(a1, b4.z, cc[1].z); cc[1].w = fmaf(a1, b4.w, cc[1].w);
            cc[2].x = fmaf(a2, b4.x, cc[2].x); cc[2].y = fmaf(a2, b4.y, cc[2].y);
            cc[2].z = fmaf(a2, b4.z, cc[2].z); cc[2].w = fmaf(a2, b4.w, cc[2].w);
            cc[3].x = fmaf(a3, b4.x, cc[3].x); cc[3].y = fmaf(a3, b4.y, cc[3].y);
            cc[3].z = fmaf(a3, b4.z, cc[3].z); cc[3].w = fmaf(a3, b4.w, cc[3].w);
        }
        __syncthreads();
    }
    float4 bs = *(const float4*)&bias[n0 + tx * 4];
#pragma unroll
    for (int i = 0; i < 4; ++i) {
        float4 r = cc[i];
        r.x += bs.x; r.y += bs.y; r.z += bs.z; r.w += bs.w;
        *(float4*)&C[(size_t)(m0 + ty * 4 + i) * 768 + n0 + tx * 4] = r;
    }
}

// ---------- LSTM via MFMA v3: 4 wgs = (dir, b-half of 16) ----------
// ALL 24 B-frags (4 gates x 6 kt) in 96 VGPRs, pinned by an asm register
// fence so the compiler cannot rematerialize the loads inside the step loop
// (R2 spilled at 96-elem array; R3/R4 remat'd -> in-loop global traffic).
// h-fragment LDS double-buffered -> one barrier/step. Pooled h written
// coalesced (wave 0, float4) to htmp[d][t][b][96].
__global__ __launch_bounds__(768, 3) void k_lstm_mfma(
    const float* __restrict__ gx, const short* __restrict__ wfrag,
    float* __restrict__ htmp)
{
    __shared__ __align__(16) short Hf[2][3072];  // h frags, double buffer

    int bid = blockIdx.x;           // d*2 + half
    int d = bid >> 1;
    int b0 = (bid & 1) * 16;
    int tid = threadIdx.x;
    int w = tid >> 6;
    int l = tid & 63;
    int lm = l & 15, lq = l >> 4;

    // all 4 gates' B-fragments in registers (24 x u4v = 96 VGPRs)
    u4v Bw[4][6];
    {
        const short* wb = wfrag + ((size_t)(d * 12 + w) * 4) * 3072 + (size_t)l * 8;
#pragma unroll
        for (int tau = 0; tau < 4; ++tau)
#pragma unroll
            for (int kt = 0; kt < 6; ++kt)
                Bw[tau][kt] = *(const u4v*)(wb + (tau * 6 + kt) * 512);
    }
    // anti-remat fence: after this, each Bw element is an opaque register value
#pragma unroll
    for (int tau = 0; tau < 4; ++tau)
#pragma unroll
        for (int kt = 0; kt < 6; ++kt)
            asm volatile("" : "+v"(Bw[tau][kt]));

    for (int i2 = tid; i2 < 1536; i2 += 768) ((uint32_t*)Hf[0])[i2] = 0u;

    float c4[4] = {0.f, 0.f, 0.f, 0.f};

    // gx: [d][t][b(32)][768]; thread needs (b0 + lq*4 + r, 16w + lm + 192*tau)
    const float* gxb = gx + (size_t)d * 6291456 + (size_t)(b0 + lq * 4) * 768 + w * 16 + lm;
    float pre[4][4];
    {
        int t0 = d ? 255 : 0;
        const float* gp = gxb + (size_t)t0 * 24576;
#pragma unroll
        for (int tau = 0; tau < 4; ++tau)
#pragma unroll
            for (int r = 0; r < 4; ++r)
                pre[tau][r] = gp[r * 768 + tau * 192];
    }

    int j = w * 16 + lm;                       // this thread's h-column
    int kt_j = j >> 5, kg_j = (j >> 3) & 3, off_j = j & 7;
    int hw_u32 = (kt_j * 512 + (kg_j * 16 + lq * 4) * 8 + (off_j & ~1)) >> 1;
    // wave-0 pooled store base: htmp[((d*256+t)*32 + b0+lm)*96 + kt*16 + lq*4]
    float* hbase = htmp + ((size_t)d * 256 * 32 + b0 + lm) * 96 + lq * 4;

    __syncthreads();

    for (int s = 0; s < 256; ++s) {
        int t = d ? 255 - s : s;
        int p = s & 1;
        f4v acc[4];
#pragma unroll
        for (int tau = 0; tau < 4; ++tau) {
            f4v a0 = {pre[tau][0], pre[tau][1], pre[tau][2], pre[tau][3]};
            acc[tau] = a0;
        }
        if (s < 255) {
            int tn = d ? 254 - s : s + 1;
            const float* gp = gxb + (size_t)tn * 24576;
#pragma unroll
            for (int tau = 0; tau < 4; ++tau)
#pragma unroll
                for (int r = 0; r < 4; ++r)
                    pre[tau][r] = gp[r * 768 + tau * 192];
        }
        bool dost = (w == 0) && (s > 0);
        int tprev = d ? t + 1 : t - 1;
        float* hst = hbase + (size_t)tprev * 3072;
#pragma unroll
        for (int kt = 0; kt < 6; ++kt) {
            s8v A = *(const s8v*)&Hf[p][kt * 512 + l * 8];
            if (dost) {
                const uint32_t* au = (const uint32_t*)&A;
                float4 pv;
                pv.x = 0.5f * (bflo(au[0]) + bfhi(au[0]));
                pv.y = 0.5f * (bflo(au[1]) + bfhi(au[1]));
                pv.z = 0.5f * (bflo(au[2]) + bfhi(au[2]));
                pv.w = 0.5f * (bflo(au[3]) + bfhi(au[3]));
                *(float4*)&hst[kt * 16] = pv;
            }
            acc[0] = __builtin_amdgcn_mfma_f32_16x16x32_bf16(
                A, __builtin_bit_cast(s8v, Bw[0][kt]), acc[0], 0, 0, 0);
            acc[1] = __builtin_amdgcn_mfma_f32_16x16x32_bf16(
                A, __builtin_bit_cast(s8v, Bw[1][kt]), acc[1], 0, 0, 0);
            acc[2] = __builtin_amdgcn_mfma_f32_16x16x32_bf16(
                A, __builtin_bit_cast(s8v, Bw[2][kt]), acc[2], 0, 0, 0);
            acc[3] = __builtin_amdgcn_mfma_f32_16x16x32_bf16(
                A, __builtin_bit_cast(s8v, Bw[3][kt]), acc[3], 0, 0, 0);
        }
        float hv[4];
#pragma unroll
        for (int r = 0; r < 4; ++r) {
            float ig = sigmoidf_(acc[0][r]);
            float fg = sigmoidf_(acc[1][r]);
            float gg = tanhf_(acc[2][r]);
            float og = sigmoidf_(acc[3][r]);
            c4[r] = fmaf(fg, c4[r], ig * gg);
            hv[r] = og * tanhf_(c4[r]);
        }
        float hp[4];
#pragma unroll
        for (int r = 0; r < 4; ++r) hp[r] = __shfl_xor(hv[r], 1);
        if ((lm & 1) == 0) {
            uint32_t* dst = (uint32_t*)Hf[p ^ 1];
#pragma unroll
            for (int r = 0; r < 4; ++r)
                dst[hw_u32 + r * 4] = f2bf(hv[r]) | (f2bf(hp[r]) << 16);
        }
        __syncthreads();
    }
    // final pooled store (h_255 lives in Hf[0])
    if (w == 0) {
        int tlast = d ? 0 : 255;
        float* hst = hbase + (size_t)tlast * 3072;
#pragma unroll
        for (int kt = 0; kt < 6; ++kt) {
            s8v A = *(const s8v*)&Hf[0][kt * 512 + l * 8];
            const uint32_t* au = (const uint32_t*)&A;
            float4 pv;
            pv.x = 0.5f * (bflo(au[0]) + bfhi(au[0]));
            pv.y = 0.5f * (bflo(au[1]) + bfhi(au[1]));
            pv.z = 0.5f * (bflo(au[2]) + bfhi(au[2]));
            pv.w = 0.5f * (bflo(au[3]) + bfhi(au[3]));
            *(float4*)&hst[kt * 16] = pv;
        }
    }
}

// ---------- htmp[d][t][b][96] -> e0[b][d*96+jp][t] ----------
__global__ __launch_bounds__(256) void k_hT(const float* __restrict__ htmp, float* __restrict__ e0)
{
    __shared__ float tl[96 * 65];
    int t0 = blockIdx.x * 64;
    int b = blockIdx.y;
    int d = blockIdx.z;
    int tid = threadIdx.x;
    for (int idx = tid; idx < 6144; idx += 256) {
        int tt = idx / 96, jp = idx % 96;
        tl[jp * 65 + tt] = htmp[(((size_t)d * 256 + t0 + tt) * 32 + b) * 96 + jp];
    }
    __syncthreads();
    for (int idx = tid; idx < 6144; idx += 256) {
        int jp = idx >> 6, tt = idx & 63;
        e0[((size_t)b * 384 + d * 96 + jp) * 256 + t0 + tt] = tl[jp * 65 + tt];
    }
}

// ---------- mu/logvar/z: per-channel linears, block per c ----------
__global__ __launch_bounds__(256) void k_muz(
    const float* __restrict__ e0, const float* __restrict__ muw, const float* __restrict__ mub,
    const float* __restrict__ lvw, const float* __restrict__ lvb, const float* __restrict__ eps,
    float* __restrict__ mu_out, float* __restrict__ lv_out, float* __restrict__ z)
{
    int c = blockIdx.x;
    int tid = threadIdx.x;
    __shared__ float eL[32 * 257];
    __shared__ float gL[48 * 33];
    for (int idx = tid; idx < 8192; idx += 256) {
        int b = idx >> 8, dd = idx & 255;
        eL[b * 257 + dd] = e0[((size_t)b * 384 + c) * 256 + dd];
    }
    __syncthreads();
    for (int rep = 0; rep < 6; ++rep) {
        int task = rep * 256 + tid;
        int b = task & 31, r = task >> 5;
        const float* row = (r < 24) ? (muw + ((size_t)c * 24 + r) * 256)
                                    : (lvw + ((size_t)c * 24 + (r - 24)) * 256);
        float acc = 0.f;
#pragma unroll 4
        for (int dd = 0; dd < 256; ++dd) acc = fmaf(eL[b * 257 + dd], row[dd], acc);
        acc += (r < 24) ? mub[c * 24 + r] : lvb[c * 24 + (r - 24)];
        gL[r * 33 + b] = acc;
    }
    __syncthreads();
    for (int rep = 0; rep < 3; ++rep) {
        int task = rep * 256 + tid;
        int b = task / 24, l = task % 24;
        float muv = gL[l * 33 + b], lvv = gL[(24 + l) * 33 + b];
        size_t oi = ((size_t)b * 384 + c) * 24 + l;
        mu_out[oi] = muv;
        lv_out[oi] = lvv;
        z[oi] = fmaf(eps[oi], __expf(0.5f * lvv), muv);
    }
}

// ---------- dec: x4[b,c,d] = sum_l z[b,c,l]*dec_w[c,d,l] + dec_b[c,d] ----------
__global__ __launch_bounds__(256) void k_dec(
    const float* __restrict__ z, const float* __restrict__ dw, const float* __restrict__ db,
    float* __restrict__ x4)
{
    int c = blockIdx.x, tid = threadIdx.x;
    __shared__ float zL[32 * 25];
    __shared__ float WdL[256 * 25];
    for (int idx = tid; idx < 768; idx += 256) {
        int b = idx / 24, l = idx % 24;
        zL[b * 25 + l] = z[((size_t)b * 384 + c) * 24 + l];
    }
    for (int idx = tid; idx < 6144; idx += 256) {
        int dd = idx / 24, l = idx % 24;
        WdL[dd * 25 + l] = dw[((size_t)c * 256 + dd) * 24 + l];
    }
    __syncthreads();
    for (int rep = 0; rep < 32; ++rep) {
        int task = rep * 256 + tid;
        int b = task >> 8, dd = task & 255;
        float acc = db[c * 256 + dd];
#pragma unroll
        for (int l = 0; l < 24; ++l) acc = fmaf(zL[b * 25 + l], WdL[dd * 25 + l], acc);
        x4[((size_t)b * 384 + c) * 256 + dd] = acc;
    }
}

// ---------- transposed conv (stride 2, k=16, pad 7) + bn + prelu; CO-tiled ----------
template<int CI, int CO, int WIN, int SPLIT, int COFULL>
__global__ __launch_bounds__(256) void k_convT(
    const float* __restrict__ in1, const float* __restrict__ in2, const float* __restrict__ w,
    const float* __restrict__ bias, const float* g, const float* bb, const float* m,
    const float* v, const float* a, float* __restrict__ out)
{
    const int WOUT = WIN * 2;
    constexpr int R = CO / 16;
    __shared__ float XL[8 * 41];
    __shared__ float WL[8 * CO * 18];
    int tid = threadIdx.x;
    int w0 = blockIdx.x * 64, b = blockIdx.z;
    int cb = blockIdx.y * CO;
    int u0 = w0 >> 1;
    int wq = tid & 15, cq = tid >> 4;
    float acc[4][R];
#pragma unroll
    for (int i = 0; i < 4; ++i)
#pragma unroll
        for (int r = 0; r < R; ++r) acc[i][r] = 0.f;

    for (int ci0 = 0; ci0 < CI; ci0 += 8) {
        __syncthreads();
        for (int idx = tid; idx < 320; idx += 256) {
            int ci = idx / 40, p = idx % 40;
            int dpos = u0 - 4 + p;
            int cig = ci0 + ci;
            float val = 0.f;
            if (dpos >= 0 && dpos < WIN)
                val = (cig < SPLIT) ? in1[((size_t)b * SPLIT + cig) * WIN + dpos]
                                    : in2[((size_t)b * (CI - SPLIT) + (cig - SPLIT)) * WIN + dpos];
            XL[ci * 41 + p] = val;
        }
        for (int idx = tid; idx < 8 * CO * 16; idx += 256) {
            int ci = idx / (CO * 16), rem = idx % (CO * 16);
            int co = rem / 16, k = rem & 15;
            WL[(ci * CO + co) * 18 + k] = w[((size_t)(ci0 + ci) * COFULL + cb + co) * 16 + k];
        }
        __syncthreads();
        for (int ci = 0; ci < 8; ++ci) {
            float xr[10];
#pragma unroll
            for (int p = 0; p < 10; ++p) xr[p] = XL[ci * 41 + 2 * wq + p];
#pragma unroll
            for (int j = 0; j < 8; ++j) {
                float xa = xr[7 - j];
                float xb = xr[8 - j];
                float xc = xr[9 - j];
#pragma unroll
                for (int r = 0; r < R; ++r) {
                    float2 wv = *(const float2*)&WL[(ci * CO + cq * R + r) * 18 + 2 * j];
                    acc[0][r] = fmaf(xa, wv.y, acc[0][r]);
                    acc[1][r] = fmaf(xb, wv.x, acc[1][r]);
                    acc[2][r] = fmaf(xb, wv.y, acc[2][r]);
                    acc[3][r] = fmaf(xc, wv.x, acc[3][r]);
                }
            }
        }
    }
    float al = a[0];
#pragma unroll
    for (int r = 0; r < R; ++r) {
        int co = cb + cq * R + r;
        float sc = g[co] * rsqrtf(v[co] + 1e-5f);
        float bi = bias[co], mm = m[co], be = bb[co];
        float4 yv;
        float* yf = (float*)&yv;
#pragma unroll
        for (int i = 0; i < 4; ++i) {
            float y = (acc[i][r] + bi - mm) * sc + be;
            yf[i] = y >= 0.f ? y : al * y;
        }
        *(float4*)&out[((size_t)b * COFULL + co) * WOUT + w0 + wq * 4] = yv;
    }
}

// ---------- fused sdconv (96->48x24 over h) + bn6 + prelu + fconv ----------
__global__ __launch_bounds__(256) void k_final(
    const float* __restrict__ u2, const float* __restrict__ x1, const float* __restrict__ wsdT,
    const float* __restrict__ sdb, const float* g, const float* bb, const float* m,
    const float* v, const float* a, const float* fcw, const float* fcb, float* __restrict__ out)
{
    __shared__ float e2L[64 * 100];
    __shared__ float WL[48 * 100];
    __shared__ float red[64 * 17];
    int tid = threadIdx.x;
    int t0 = blockIdx.x * 64, h = blockIdx.y, b = blockIdx.z;
    for (int idx = tid; idx < 6144; idx += 256) {
        int ci = idx >> 6, tt = idx & 63;
        float vv = (ci < 48) ? u2[((size_t)b * 48 + ci) * 1024 + t0 + tt]
                             : x1[((size_t)b * 48 + (ci - 48)) * 1024 + t0 + tt];
        e2L[tt * 100 + ci] = vv;
    }
    for (int idx = tid; idx < 4608; idx += 256) {
        WL[(idx / 96) * 100 + (idx % 96)] = wsdT[(size_t)h * 4608 + idx];
    }
    __syncthreads();
    int tx = tid & 15, ty = tid >> 4;
    float accv[4][3] = {};
    for (int c4 = 0; c4 < 24; ++c4) {
        float4 e4[4], w4[3];
#pragma unroll
        for (int i = 0; i < 4; ++i) e4[i] = *(const float4*)&e2L[(tx + 16 * i) * 100 + c4 * 4];
#pragma unroll
        for (int r = 0; r < 3; ++r) w4[r] = *(const float4*)&WL[(ty * 3 + r) * 100 + c4 * 4];
#pragma unroll
        for (int i = 0; i < 4; ++i)
#pragma unroll
            for (int r = 0; r < 3; ++r) {
                accv[i][r] = fmaf(e4[i].x, w4[r].x, accv[i][r]);
                accv[i][r] = fmaf(e4[i].y, w4[r].y, accv[i][r]);
                accv[i][r] = fmaf(e4[i].z, w4[r].z, accv[i][r]);
                accv[i][r] = fmaf(e4[i].w, w4[r].w, accv[i][r]);
            }
    }
    float al = a[0];
    float psum[4] = {};
#pragma unroll
    for (int r = 0; r < 3; ++r) {
        int co = ty * 3 + r;
        float sc = g[co] * rsqrtf(v[co] + 1e-5f);
        float fw = fcw[co], bi = sdb[co], mm = m[co], be = bb[co];
#pragma unroll
        for (int i = 0; i < 4; ++i) {
            float y = (accv[i][r] + bi - mm) * sc + be;
            y = y >= 0.f ? y : al * y;
            psum[i] = fmaf(fw, y, psum[i]);
        }
    }
#pragma unroll
    for (int i = 0; i < 4; ++i) red[(i * 16 + tx) * 17 + ty] = psum[i];
    __syncthreads();
    if (tid < 64) {
        float s = fcb[0];
#pragma unroll
        for (int y2 = 0; y2 < 16; ++y2) s += red[tid * 17 + y2];
        out[((size_t)b * 24 + h) * 1024 + t0 + tid] = s;
    }
}

// ---------- launch ----------
extern "C" void kernel_launch(void* const* d_in, const int* in_sizes, int n_in,
                              void* d_out, int out_size, void* d_ws, size_t ws_size,
                              hipStream_t stream)
{
    (void)in_sizes; (void)n_in; (void)out_size; (void)ws_size;
    const float* x        = (const float*)d_in[0];
    const float* eps      = (const float*)d_in[1];
    const float* sconv_w  = (const float*)d_in[2];
    const float* sconv_b  = (const float*)d_in[3];
    const float* tconv1_w = (const float*)d_in[4];
    const float* tconv1_b = (const float*)d_in[5];
    const float* tconv2_w = (const float*)d_in[6];
    const float* tconv2_b = (const float*)d_in[7];
    const float *bn1g=(const float*)d_in[8],  *bn1b=(const float*)d_in[9],  *bn1m=(const float*)d_in[10], *bn1v=(const float*)d_in[11], *a1=(const float*)d_in[12];
    const float *bn2g=(const float*)d_in[13], *bn2b=(const float*)d_in[14], *bn2m=(const float*)d_in[15], *bn2v=(const float*)d_in[16], *a2=(const float*)d_in[17];
    const float *bn3g=(const float*)d_in[18], *bn3b=(const float*)d_in[19], *bn3m=(const float*)d_in[20], *bn3v=(const float*)d_in[21], *a3=(const float*)d_in[22];
    const float *bn4g=(const float*)d_in[23], *bn4b=(const float*)d_in[24], *bn4m=(const float*)d_in[25], *bn4v=(const float*)d_in[26], *a4=(const float*)d_in[27];
    const float *bn5g=(const float*)d_in[28], *bn5b=(const float*)d_in[29], *bn5m=(const float*)d_in[30], *bn5v=(const float*)d_in[31], *a5=(const float*)d_in[32];
    const float *bn6g=(const float*)d_in[33], *bn6b=(const float*)d_in[34], *bn6m=(const float*)d_in[35], *bn6v=(const float*)d_in[36], *a6=(const float*)d_in[37];
    const float *wihf=(const float*)d_in[38], *whhf=(const float*)d_in[39], *bihf=(const float*)d_in[40], *bhhf=(const float*)d_in[41];
    const float *wihb=(const float*)d_in[42], *whhb=(const float*)d_in[43], *bihb=(const float*)d_in[44], *bhhb=(const float*)d_in[45];
    const float *mu_w=(const float*)d_in[46], *mu_b=(const float*)d_in[47];
    const float *lv_w=(const float*)d_in[48], *lv_b=(const float*)d_in[49];
    const float *dec_w=(const float*)d_in[50], *dec_b=(const float*)d_in[51];
    const float *dconv1_w=(const float*)d_in[52], *dconv1_b=(const float*)d_in[53];
    const float *dconv2_w=(const float*)d_in[54], *dconv2_b=(const float*)d_in[55];
    const float *sdconv_w=(const float*)d_in[56], *sdconv_b=(const float*)d_in[57];
    const float *fconv_w=(const float*)d_in[58], *fconv_b=(const float*)d_in[59];

    float* ws = (float*)d_ws;
    float* x1   = ws + 0;
    float* x2   = ws + 1572864;
    float* e0   = ws + 3145728;       // [B][384][256]; ch 192.. written by tconv2
    float* x3s  = ws + 6291456;       // [8192][192]  (dead after gemms)
    float* htmp = ws + 6291456;       // overlay on x3s: [2][256][32][96]
    float* wihT = ws + 7864320;       // [2][192][768]
    uint32_t* wfrag = (uint32_t*)(ws + 8159232);  // [2][12][4][6][64][4] u32 (bf16 B-frags)
    float* bsum = ws + 8306688;       // [2][768]
    float* gx   = ws + 8308736;       // [2][256][32][768]  (dead after lstm)
    float* z    = ws + 8308736;       // overlay on gx
    float* x4   = ws + 8603648;       // overlay on gx
    float* u1   = ws + 11749376;      // overlay on gx
    float* u2   = ws + 13322240;      // overlay on gx
    float* wsdT = ws + 20891648;      // [24][48][96]

    float* out0 = (float*)d_out;
    float* muo  = out0 + 786432;
    float* lvo  = muo + 294912;

    k_prep<<<2166, 256, 0, stream>>>(wihf, wihb, whhf, whhb, bihf, bhhf, bihb, bhhb,
                                     sdconv_w, wihT, wfrag, bsum, wsdT);
    k_sconv<<<dim3(4, 48, 32), 256, 0, stream>>>(x, sconv_w, sconv_b, bn1g, bn1b, bn1m, bn1v, a1, x1);
    k_tconv<48, 96, 512, 96><<<dim3(8, 6, 32), 256, 0, stream>>>(
        x1, tconv1_w, tconv1_b, bn2g, bn2b, bn2m, bn2v, a2, x2);
    k_tconv<96, 192, 256, 384><<<dim3(4, 12, 32), 256, 0, stream>>>(
        x2, tconv2_w, tconv2_b, bn3g, bn3b, bn3m, bn3v, a3, e0 + 49152);
    k_x3s<<<dim3(4, 32), 256, 0, stream>>>(e0, x3s);
    k_gemm<<<dim3(12, 128), 256, 0, stream>>>(x3s, wihT, bsum, gx);
    k_gemm<<<dim3(12, 128), 256, 0, stream>>>(x3s, wihT + 147456, bsum + 768, gx + 6291456);
    k_lstm_mfma<<<4, 768, 0, stream>>>(gx, (const short*)wfrag, htmp);
    k_hT<<<dim3(4, 32, 2), 256, 0, stream>>>(htmp, e0);
    k_muz<<<384, 256, 0, stream>>>(e0, mu_w, mu_b, lv_w, lv_b, eps, muo, lvo, z);
    k_dec<<<384, 256, 0, stream>>>(z, dec_w, dec_b, x4);
    k_convT<384, 48, 256, 384, 96><<<dim3(8, 2, 32), 256, 0, stream>>>(
        x4, x4, dconv1_w, dconv1_b, bn4g, bn4b, bn4m, bn4v, a4, u1);
    k_convT<192, 48, 512, 96, 48><<<dim3(16, 1, 32), 256, 0, stream>>>(
        u1, x2, dconv2_w, dconv2_b, bn5g, bn5b, bn5m, bn5v, a5, u2);
    k_final<<<dim3(16, 24, 32), 256, 0, stream>>>(
        u2, x1, wsdT, sdconv_b, bn6g, bn6b, bn6m, bn6v, a6, fconv_w, fconv_b, out0);
}

// Round 6
// 1654.615 us; speedup vs baseline: 1.0505x; 1.0505x over previous
//
#include <hip/hip_runtime.h>
#include <cstdint>

#define DI __device__ __forceinline__

typedef __attribute__((ext_vector_type(8))) short s8v;     // 8 bf16 = 4 VGPRs
typedef __attribute__((ext_vector_type(4))) float f4v;     // MFMA acc
typedef __attribute__((ext_vector_type(4))) uint32_t u4v;  // 4 VGPRs

// ---------- helpers ----------
DI float sigmoidf_(float x) {
    return __builtin_amdgcn_rcpf(1.f + __expf(-x));
}
DI float tanhf_(float x) {
    return fmaf(-2.f, __builtin_amdgcn_rcpf(1.f + __expf(2.f * x)), 1.f);
}
DI uint32_t f2bf(float f) {
    uint32_t u = __float_as_uint(f);
    return (u + 0x7fffu + ((u >> 16) & 1u)) >> 16;
}
DI float bflo(uint32_t u) { return __uint_as_float(u << 16); }
DI float bfhi(uint32_t u) { return __uint_as_float(u & 0xffff0000u); }
// LDS-only barrier: __syncthreads() drains vmcnt(0) too, which stalls on the
// in-flight gx prefetch every step. Only LDS ordering is required.
DI void lgkm_barrier() {
    asm volatile("s_waitcnt lgkmcnt(0)\n\ts_barrier" ::: "memory");
}

// ---------- prep: weight packs (wfrag | bsum | wsdT) ----------
__global__ __launch_bounds__(256) void k_prep(
    const float* whhf, const float* whhb,
    const float* bihf, const float* bhhf, const float* bihb, const float* bhhb,
    const float* sdw,
    uint32_t* wfrag, float* bsum, float* wsdT)
{
    int i = blockIdx.x * 256 + threadIdx.x;
    if (i < 147456) {
        // B-fragment pack for MFMA 16x16x32 bf16: B[k][n], n=lane&15, k=(lane>>4)*8+jj
        int d = i / 73728, r = i % 73728;
        int w = r / 6144, r2 = r % 6144;
        int tau = r2 / 1536, r3 = r2 % 1536;
        int kt = r3 / 256, r4 = r3 % 256;
        int lane = r4 / 4, jp = r4 % 4;
        int n = 16 * (w + 12 * tau) + (lane & 15);
        int k0 = kt * 32 + (lane >> 4) * 8 + jp * 2;
        const float* whh = d ? whhb : whhf;   // w_hh[n][k] row-major (4H8 x H8)
        uint32_t lo = f2bf(whh[n * 192 + k0]);
        uint32_t hi = f2bf(whh[n * 192 + k0 + 1]);
        wfrag[i] = lo | (hi << 16);
        return;
    }
    int k = i - 147456;
    if (k < 1536) {
        int d = k / 768, g = k % 768;
        bsum[k] = d ? (bihb[g] + bhhb[g]) : (bihf[g] + bhhf[g]);
        return;
    }
    int l = k - 1536;
    if (l < 110592) {
        int h = l / 4608, rem = l % 4608;
        int co = rem / 96, ci = rem % 96;
        wsdT[l] = sdw[(ci * 48 + co) * 24 + h];
    }
}

// ---------- wihT via LDS-tiled transpose (both sides coalesced) ----------
__global__ __launch_bounds__(256) void k_prepT(
    const float* wihf, const float* wihb, float* wihT)
{
    __shared__ float tl[64 * 65];
    int ii0 = blockIdx.x * 64, g0 = blockIdx.y * 64, d = blockIdx.z;
    const float* w = d ? wihb : wihf;   // w[g][ii], 768x192
    int tid = threadIdx.x;
    for (int r = tid; r < 4096; r += 256) {
        int gg = r >> 6, ii = r & 63;
        tl[ii * 65 + gg] = w[(size_t)(g0 + gg) * 192 + ii0 + ii];
    }
    __syncthreads();
    for (int r = tid; r < 4096; r += 256) {
        int ii = r >> 6, gg = r & 63;
        wihT[(size_t)d * 147456 + (size_t)(ii0 + ii) * 768 + g0 + gg] = tl[ii * 65 + gg];
    }
}

// ---------- K1: sconv (24->48 over H) + bn1 + prelu ----------
__global__ __launch_bounds__(256) void k_sconv(
    const float* __restrict__ x, const float* __restrict__ w, const float* __restrict__ bias,
    const float* g, const float* bb, const float* m, const float* v, const float* a,
    float* __restrict__ x1)
{
    int t = blockIdx.x * 256 + threadIdx.x;
    int co = blockIdx.y;
    int b = blockIdx.z;
    const float* xb = x + (size_t)b * 24 * 1024 + t;
    float acc = bias[co];
#pragma unroll
    for (int h = 0; h < 24; ++h) acc = fmaf(xb[h * 1024], w[co * 24 + h], acc);
    float sc = g[co] * rsqrtf(v[co] + 1e-5f);
    float y = (acc - m[co]) * sc + bb[co];
    float al = a[0];
    y = y >= 0.f ? y : al * y;
    x1[((size_t)b * 48 + co) * 1024 + t] = y;
}

// ---------- K2/K3: strided conv (stride 2, k=16, pad 7) + bn + prelu ----------
template<int CI, int CO, int WOUT, int BSTR>
__global__ __launch_bounds__(256) void k_tconv(
    const float* __restrict__ xin, const float* __restrict__ w, const float* __restrict__ bias,
    const float* g, const float* bb, const float* m, const float* v, const float* a,
    float* __restrict__ out)
{
    const int WIN = WOUT * 2;
    __shared__ float XL[CI][144];
    int tid = threadIdx.x;
    int w0 = blockIdx.x * 64;
    int b = blockIdx.z;
    for (int idx = tid; idx < CI * 144; idx += 256) {
        int ci = idx / 144, p = idx % 144;
        int gp = 2 * w0 - 7 + p;
        XL[ci][p] = (gp >= 0 && gp < WIN) ? xin[((size_t)b * CI + ci) * WIN + gp] : 0.f;
    }
    __syncthreads();
    int tw = tid & 63, cg = tid >> 6;
    int co0 = blockIdx.y * 16 + cg * 4;
    co0 = __builtin_amdgcn_readfirstlane(co0);
    const float* wb = w + (size_t)co0 * CI * 16;
    float acc[4] = {bias[co0], bias[co0 + 1], bias[co0 + 2], bias[co0 + 3]};
    for (int ci = 0; ci < CI; ++ci) {
#pragma unroll
        for (int k = 0; k < 16; ++k) {
            float xv = XL[ci][2 * tw + k];
            acc[0] = fmaf(xv, wb[(0 * CI + ci) * 16 + k], acc[0]);
            acc[1] = fmaf(xv, wb[(1 * CI + ci) * 16 + k], acc[1]);
            acc[2] = fmaf(xv, wb[(2 * CI + ci) * 16 + k], acc[2]);
            acc[3] = fmaf(xv, wb[(3 * CI + ci) * 16 + k], acc[3]);
        }
    }
    float al = a[0];
#pragma unroll
    for (int r = 0; r < 4; ++r) {
        int co = co0 + r;
        float sc = g[co] * rsqrtf(v[co] + 1e-5f);
        float y = (acc[r] - m[co]) * sc + bb[co];
        y = y >= 0.f ? y : al * y;
        out[((size_t)b * BSTR + co) * WOUT + w0 + tw] = y;
    }
}

// ---------- x3s build: [t*32+b][192] from e0[b][192+i][t] ----------
__global__ __launch_bounds__(256) void k_x3s(const float* __restrict__ e0, float* __restrict__ x3s)
{
    __shared__ float tl[64 * 193];
    int t0 = blockIdx.x * 64, b = blockIdx.y;
    int tid = threadIdx.x;
    for (int idx = tid; idx < 192 * 64; idx += 256) {
        int i = idx >> 6, tt = idx & 63;
        tl[tt * 193 + i] = e0[((size_t)b * 384 + 192 + i) * 256 + t0 + tt];
    }
    __syncthreads();
    for (int idx = tid; idx < 64 * 192; idx += 256) {
        int tt = idx / 192, ii = idx % 192;
        x3s[((size_t)(t0 + tt) * 32 + b) * 192 + ii] = tl[tt * 193 + ii];
    }
}

// ---------- tiled GEMM: C[8192x768] = A[8192x192] * B[192x768] + bias[768] ----------
__global__ __launch_bounds__(256) void k_gemm(
    const float* __restrict__ A, const float* __restrict__ Bm,
    const float* __restrict__ bias, float* __restrict__ C)
{
    __shared__ float AL[64 * 17];
    __shared__ float BL[16 * 68];
    int tid = threadIdx.x;
    int n0 = blockIdx.x * 64, m0 = blockIdx.y * 64;
    int tx = tid & 15, ty = tid >> 4;
    float4 cc[4] = {};
    for (int k0 = 0; k0 < 192; k0 += 16) {
        for (int idx = tid; idx < 1024; idx += 256) {
            int r = idx >> 4, c = idx & 15;
            AL[r * 17 + c] = A[(size_t)(m0 + r) * 192 + k0 + c];
        }
        for (int idx = tid; idx < 1024; idx += 256) {
            int kk = idx >> 6, jj = idx & 63;
            BL[kk * 68 + jj] = Bm[(size_t)(k0 + kk) * 768 + n0 + jj];
        }
        __syncthreads();
#pragma unroll
        for (int kk = 0; kk < 16; ++kk) {
            float4 b4 = *(const float4*)&BL[kk * 68 + tx * 4];
            float a0 = AL[(ty * 4 + 0) * 17 + kk];
            float a1 = AL[(ty * 4 + 1) * 17 + kk];
            float a2 = AL[(ty * 4 + 2) * 17 + kk];
            float a3 = AL[(ty * 4 + 3) * 17 + kk];
            cc[0].x = fmaf(a0, b4.x, cc[0].x); cc[0].y = fmaf(a0, b4.y, cc[0].y);
            cc[0].z = fmaf(a0, b4.z, cc[0].z); cc[0].w = fmaf(a0, b4.w, cc[0].w);
            cc[1].x = fmaf(a1, b4.x, cc[1].x); cc[1].y = fmaf(a1, b4.y, cc[1].y);
            cc[1].z = fmaf(a1, b4.z, cc[1].z); cc[1].w = fmaf(a1, b4.w, cc[1].w);
            cc[2].x = fmaf(a2, b4.x, cc[2].x); cc[2].y = fmaf(a2, b4.y, cc[2].y);
            cc[2].z = fmaf(a2, b4.z, cc[2].z); cc[2].w = fmaf(a2, b4.w, cc[2].w);
            cc[3].x = fmaf(a3, b4.x, cc[3].x); cc[3].y = fmaf(a3, b4.y, cc[3].y);
            cc[3].z = fmaf(a3, b4.z, cc[3].z); cc[3].w = fmaf(a3, b4.w, cc[3].w);
        }
        __syncthreads();
    }
    float4 bs = *(const float4*)&bias[n0 + tx * 4];
#pragma unroll
    for (int i = 0; i < 4; ++i) {
        float4 r = cc[i];
        r.x += bs.x; r.y += bs.y; r.z += bs.z; r.w += bs.w;
        *(float4*)&C[(size_t)(m0 + ty * 4 + i) * 768 + n0 + tx * 4] = r;
    }
}

// ---------- LSTM via MFMA v4: 4 wgs = (dir, b-half of 16) ----------
// All 24 B-frags pinned in 96 VGPRs via IN-LOOP asm in-out fences: each
// iteration's asm "modifies" the values, creating a loop-carried register
// dependency -> reloading from memory is now ILLEGAL (not just discouraged).
// lgkm-only barrier per step (no vmcnt drain -> gx prefetch pipelines).
// Pooled h stores spread over waves 0..5 (kt == w).
__global__ __launch_bounds__(768, 3) void k_lstm_mfma(
    const float* __restrict__ gx, const short* __restrict__ wfrag,
    float* __restrict__ htmp)
{
    __shared__ __align__(16) short Hf[2][3072];  // h frags, double buffer

    int bid = blockIdx.x;           // d*2 + half
    int d = bid >> 1;
    int b0 = (bid & 1) * 16;
    int tid = threadIdx.x;
    int w = tid >> 6;
    int l = tid & 63;
    int lm = l & 15, lq = l >> 4;

    // all 4 gates' B-fragments in registers (24 x u4v = 96 VGPRs)
    u4v Bw[4][6];
    {
        const short* wb = wfrag + ((size_t)(d * 12 + w) * 4) * 3072 + (size_t)l * 8;
#pragma unroll
        for (int tau = 0; tau < 4; ++tau)
#pragma unroll
            for (int kt = 0; kt < 6; ++kt)
                Bw[tau][kt] = *(const u4v*)(wb + (tau * 6 + kt) * 512);
    }
    for (int i2 = tid; i2 < 1536; i2 += 768) ((uint32_t*)Hf[0])[i2] = 0u;

    float c4[4] = {0.f, 0.f, 0.f, 0.f};

    // gx: [d][t][b(32)][768]; thread needs (b0 + lq*4 + r, 16w + lm + 192*tau)
    const float* gxb = gx + (size_t)d * 6291456 + (size_t)(b0 + lq * 4) * 768 + w * 16 + lm;
    float pre[4][4];
    {
        const float* gp = gxb + (size_t)(d ? 255 : 0) * 24576;
#pragma unroll
        for (int tau = 0; tau < 4; ++tau)
#pragma unroll
            for (int r = 0; r < 4; ++r)
                pre[tau][r] = gp[r * 768 + tau * 192];
    }
    // per-r stepping pointers at t(1); tau offsets (0/768/1536/2304 B) fit imm
    ptrdiff_t dstep = d ? -24576 : 24576;
    const float* pr0 = gxb + (size_t)(d ? 254 : 1) * 24576;
    const float* pr1 = pr0 + 768;
    const float* pr2 = pr0 + 1536;
    const float* pr3 = pr0 + 2304;

    int j = w * 16 + lm;                       // this thread's h-column
    int kt_j = j >> 5, kg_j = (j >> 3) & 3, off_j = j & 7;
    int hw_u32 = (kt_j * 512 + (kg_j * 16 + lq * 4) * 8 + (off_j & ~1)) >> 1;
    // pooled store base for this wave's kt (= w): htmp[((d*256+t)*32+b0+lm)*96 + w*16 + lq*4]
    float* hbase = htmp + ((size_t)d * 8192 + b0 + lm) * 96 + w * 16 + lq * 4;

    __syncthreads();

    for (int s = 0; s < 256; ++s) {
        // loop-carried register pin: memory reload now incorrect, must stay in VGPRs
        asm volatile("" : "+v"(Bw[0][0]), "+v"(Bw[0][1]), "+v"(Bw[0][2]),
                          "+v"(Bw[0][3]), "+v"(Bw[0][4]), "+v"(Bw[0][5]));
        asm volatile("" : "+v"(Bw[1][0]), "+v"(Bw[1][1]), "+v"(Bw[1][2]),
                          "+v"(Bw[1][3]), "+v"(Bw[1][4]), "+v"(Bw[1][5]));
        asm volatile("" : "+v"(Bw[2][0]), "+v"(Bw[2][1]), "+v"(Bw[2][2]),
                          "+v"(Bw[2][3]), "+v"(Bw[2][4]), "+v"(Bw[2][5]));
        asm volatile("" : "+v"(Bw[3][0]), "+v"(Bw[3][1]), "+v"(Bw[3][2]),
                          "+v"(Bw[3][3]), "+v"(Bw[3][4]), "+v"(Bw[3][5]));
        int t = d ? 255 - s : s;
        int p = s & 1;
        f4v acc[4];
#pragma unroll
        for (int tau = 0; tau < 4; ++tau) {
            f4v a0 = {pre[tau][0], pre[tau][1], pre[tau][2], pre[tau][3]};
            acc[tau] = a0;
        }
        if (s < 255) {
#pragma unroll
            for (int tau = 0; tau < 4; ++tau) pre[tau][0] = pr0[tau * 192];
#pragma unroll
            for (int tau = 0; tau < 4; ++tau) pre[tau][1] = pr1[tau * 192];
#pragma unroll
            for (int tau = 0; tau < 4; ++tau) pre[tau][2] = pr2[tau * 192];
#pragma unroll
            for (int tau = 0; tau < 4; ++tau) pre[tau][3] = pr3[tau * 192];
            pr0 += dstep; pr1 += dstep; pr2 += dstep; pr3 += dstep;
        }
        int tprev = d ? t + 1 : t - 1;
        float* hst = hbase + (size_t)tprev * 3072;
#pragma unroll
        for (int kt = 0; kt < 6; ++kt) {
            s8v A = *(const s8v*)&Hf[p][kt * 512 + l * 8];
            if (w == kt && s > 0) {     // wave kt stores pooled h_{t-1} (reuses its A)
                const uint32_t* au = (const uint32_t*)&A;
                float4 pv;
                pv.x = 0.5f * (bflo(au[0]) + bfhi(au[0]));
                pv.y = 0.5f * (bflo(au[1]) + bfhi(au[1]));
                pv.z = 0.5f * (bflo(au[2]) + bfhi(au[2]));
                pv.w = 0.5f * (bflo(au[3]) + bfhi(au[3]));
                *(float4*)hst = pv;
            }
            acc[0] = __builtin_amdgcn_mfma_f32_16x16x32_bf16(
                A, __builtin_bit_cast(s8v, Bw[0][kt]), acc[0], 0, 0, 0);
            acc[1] = __builtin_amdgcn_mfma_f32_16x16x32_bf16(
                A, __builtin_bit_cast(s8v, Bw[1][kt]), acc[1], 0, 0, 0);
            acc[2] = __builtin_amdgcn_mfma_f32_16x16x32_bf16(
                A, __builtin_bit_cast(s8v, Bw[2][kt]), acc[2], 0, 0, 0);
            acc[3] = __builtin_amdgcn_mfma_f32_16x16x32_bf16(
                A, __builtin_bit_cast(s8v, Bw[3][kt]), acc[3], 0, 0, 0);
        }
        float hv[4];
#pragma unroll
        for (int r = 0; r < 4; ++r) {
            float ig = sigmoidf_(acc[0][r]);
            float fg = sigmoidf_(acc[1][r]);
            float gg = tanhf_(acc[2][r]);
            float og = sigmoidf_(acc[3][r]);
            c4[r] = fmaf(fg, c4[r], ig * gg);
            hv[r] = og * tanhf_(c4[r]);
        }
        float hp[4];
#pragma unroll
        for (int r = 0; r < 4; ++r) hp[r] = __shfl_xor(hv[r], 1);
        if ((lm & 1) == 0) {
            uint32_t* dst = (uint32_t*)Hf[p ^ 1];
#pragma unroll
            for (int r = 0; r < 4; ++r)
                dst[hw_u32 + r * 4] = f2bf(hv[r]) | (f2bf(hp[r]) << 16);
        }
        lgkm_barrier();
    }
    // final pooled store (h_last lives in Hf[0]); wave w<6 handles kt=w
    if (w < 6) {
        int tlast = d ? 0 : 255;
        float* hst = hbase + (size_t)tlast * 3072;
        s8v A = *(const s8v*)&Hf[0][w * 512 + l * 8];
        const uint32_t* au = (const uint32_t*)&A;
        float4 pv;
        pv.x = 0.5f * (bflo(au[0]) + bfhi(au[0]));
        pv.y = 0.5f * (bflo(au[1]) + bfhi(au[1]));
        pv.z = 0.5f * (bflo(au[2]) + bfhi(au[2]));
        pv.w = 0.5f * (bflo(au[3]) + bfhi(au[3]));
        *(float4*)hst = pv;
    }
}

// ---------- htmp[d][t][b][96] -> e0[b][d*96+jp][t] ----------
__global__ __launch_bounds__(256) void k_hT(const float* __restrict__ htmp, float* __restrict__ e0)
{
    __shared__ float tl[96 * 65];
    int t0 = blockIdx.x * 64;
    int b = blockIdx.y;
    int d = blockIdx.z;
    int tid = threadIdx.x;
    for (int idx = tid; idx < 6144; idx += 256) {
        int tt = idx / 96, jp = idx % 96;
        tl[jp * 65 + tt] = htmp[(((size_t)d * 256 + t0 + tt) * 32 + b) * 96 + jp];
    }
    __syncthreads();
    for (int idx = tid; idx < 6144; idx += 256) {
        int jp = idx >> 6, tt = idx & 63;
        e0[((size_t)b * 384 + d * 96 + jp) * 256 + t0 + tt] = tl[jp * 65 + tt];
    }
}

// ---------- mu/logvar/z: per-channel linears, block per c ----------
__global__ __launch_bounds__(256) void k_muz(
    const float* __restrict__ e0, const float* __restrict__ muw, const float* __restrict__ mub,
    const float* __restrict__ lvw, const float* __restrict__ lvb, const float* __restrict__ eps,
    float* __restrict__ mu_out, float* __restrict__ lv_out, float* __restrict__ z)
{
    int c = blockIdx.x;
    int tid = threadIdx.x;
    __shared__ float eL[32 * 257];
    __shared__ float gL[48 * 33];
    for (int idx = tid; idx < 8192; idx += 256) {
        int b = idx >> 8, dd = idx & 255;
        eL[b * 257 + dd] = e0[((size_t)b * 384 + c) * 256 + dd];
    }
    __syncthreads();
    for (int rep = 0; rep < 6; ++rep) {
        int task = rep * 256 + tid;
        int b = task & 31, r = task >> 5;
        const float* row = (r < 24) ? (muw + ((size_t)c * 24 + r) * 256)
                                    : (lvw + ((size_t)c * 24 + (r - 24)) * 256);
        float acc = 0.f;
#pragma unroll 4
        for (int dd = 0; dd < 256; ++dd) acc = fmaf(eL[b * 257 + dd], row[dd], acc);
        acc += (r < 24) ? mub[c * 24 + r] : lvb[c * 24 + (r - 24)];
        gL[r * 33 + b] = acc;
    }
    __syncthreads();
    for (int rep = 0; rep < 3; ++rep) {
        int task = rep * 256 + tid;
        int b = task / 24, l = task % 24;
        float muv = gL[l * 33 + b], lvv = gL[(24 + l) * 33 + b];
        size_t oi = ((size_t)b * 384 + c) * 24 + l;
        mu_out[oi] = muv;
        lv_out[oi] = lvv;
        z[oi] = fmaf(eps[oi], __expf(0.5f * lvv), muv);
    }
}

// ---------- dec: x4[b,c,d] = sum_l z[b,c,l]*dec_w[c,d,l] + dec_b[c,d] ----------
__global__ __launch_bounds__(256) void k_dec(
    const float* __restrict__ z, const float* __restrict__ dw, const float* __restrict__ db,
    float* __restrict__ x4)
{
    int c = blockIdx.x, tid = threadIdx.x;
    __shared__ float zL[32 * 25];
    __shared__ float WdL[256 * 25];
    for (int idx = tid; idx < 768; idx += 256) {
        int b = idx / 24, l = idx % 24;
        zL[b * 25 + l] = z[((size_t)b * 384 + c) * 24 + l];
    }
    for (int idx = tid; idx < 6144; idx += 256) {
        int dd = idx / 24, l = idx % 24;
        WdL[dd * 25 + l] = dw[((size_t)c * 256 + dd) * 24 + l];
    }
    __syncthreads();
    for (int rep = 0; rep < 32; ++rep) {
        int task = rep * 256 + tid;
        int b = task >> 8, dd = task & 255;
        float acc = db[c * 256 + dd];
#pragma unroll
        for (int l = 0; l < 24; ++l) acc = fmaf(zL[b * 25 + l], WdL[dd * 25 + l], acc);
        x4[((size_t)b * 384 + c) * 256 + dd] = acc;
    }
}

// ---------- transposed conv (stride 2, k=16, pad 7) + bn + prelu; CO-tiled ----------
template<int CI, int CO, int WIN, int SPLIT, int COFULL>
__global__ __launch_bounds__(256) void k_convT(
    const float* __restrict__ in1, const float* __restrict__ in2, const float* __restrict__ w,
    const float* __restrict__ bias, const float* g, const float* bb, const float* m,
    const float* v, const float* a, float* __restrict__ out)
{
    const int WOUT = WIN * 2;
    constexpr int R = CO / 16;
    __shared__ float XL[8 * 41];
    __shared__ float WL[8 * CO * 18];
    int tid = threadIdx.x;
    int w0 = blockIdx.x * 64, b = blockIdx.z;
    int cb = blockIdx.y * CO;
    int u0 = w0 >> 1;
    int wq = tid & 15, cq = tid >> 4;
    float acc[4][R];
#pragma unroll
    for (int i = 0; i < 4; ++i)
#pragma unroll
        for (int r = 0; r < R; ++r) acc[i][r] = 0.f;

    for (int ci0 = 0; ci0 < CI; ci0 += 8) {
        __syncthreads();
        for (int idx = tid; idx < 320; idx += 256) {
            int ci = idx / 40, p = idx % 40;
            int dpos = u0 - 4 + p;
            int cig = ci0 + ci;
            float val = 0.f;
            if (dpos >= 0 && dpos < WIN)
                val = (cig < SPLIT) ? in1[((size_t)b * SPLIT + cig) * WIN + dpos]
                                    : in2[((size_t)b * (CI - SPLIT) + (cig - SPLIT)) * WIN + dpos];
            XL[ci * 41 + p] = val;
        }
        for (int idx = tid; idx < 8 * CO * 16; idx += 256) {
            int ci = idx / (CO * 16), rem = idx % (CO * 16);
            int co = rem / 16, k = rem & 15;
            WL[(ci * CO + co) * 18 + k] = w[((size_t)(ci0 + ci) * COFULL + cb + co) * 16 + k];
        }
        __syncthreads();
        for (int ci = 0; ci < 8; ++ci) {
            float xr[10];
#pragma unroll
            for (int p = 0; p < 10; ++p) xr[p] = XL[ci * 41 + 2 * wq + p];
#pragma unroll
            for (int j = 0; j < 8; ++j) {
                float xa = xr[7 - j];
                float xb = xr[8 - j];
                float xc = xr[9 - j];
#pragma unroll
                for (int r = 0; r < R; ++r) {
                    float2 wv = *(const float2*)&WL[(ci * CO + cq * R + r) * 18 + 2 * j];
                    acc[0][r] = fmaf(xa, wv.y, acc[0][r]);
                    acc[1][r] = fmaf(xb, wv.x, acc[1][r]);
                    acc[2][r] = fmaf(xb, wv.y, acc[2][r]);
                    acc[3][r] = fmaf(xc, wv.x, acc[3][r]);
                }
            }
        }
    }
    float al = a[0];
#pragma unroll
    for (int r = 0; r < R; ++r) {
        int co = cb + cq * R + r;
        float sc = g[co] * rsqrtf(v[co] + 1e-5f);
        float bi = bias[co], mm = m[co], be = bb[co];
        float4 yv;
        float* yf = (float*)&yv;
#pragma unroll
        for (int i = 0; i < 4; ++i) {
            float y = (acc[i][r] + bi - mm) * sc + be;
            yf[i] = y >= 0.f ? y : al * y;
        }
        *(float4*)&out[((size_t)b * COFULL + co) * WOUT + w0 + wq * 4] = yv;
    }
}

// ---------- fused sdconv (96->48x24 over h) + bn6 + prelu + fconv ----------
__global__ __launch_bounds__(256) void k_final(
    const float* __restrict__ u2, const float* __restrict__ x1, const float* __restrict__ wsdT,
    const float* __restrict__ sdb, const float* g, const float* bb, const float* m,
    const float* v, const float* a, const float* fcw, const float* fcb, float* __restrict__ out)
{
    __shared__ float e2L[64 * 100];
    __shared__ float WL[48 * 100];
    __shared__ float red[64 * 17];
    int tid = threadIdx.x;
    int t0 = blockIdx.x * 64, h = blockIdx.y, b = blockIdx.z;
    for (int idx = tid; idx < 6144; idx += 256) {
        int ci = idx >> 6, tt = idx & 63;
        float vv = (ci < 48) ? u2[((size_t)b * 48 + ci) * 1024 + t0 + tt]
                             : x1[((size_t)b * 48 + (ci - 48)) * 1024 + t0 + tt];
        e2L[tt * 100 + ci] = vv;
    }
    for (int idx = tid; idx < 4608; idx += 256) {
        WL[(idx / 96) * 100 + (idx % 96)] = wsdT[(size_t)h * 4608 + idx];
    }
    __syncthreads();
    int tx = tid & 15, ty = tid >> 4;
    float accv[4][3] = {};
    for (int c4 = 0; c4 < 24; ++c4) {
        float4 e4[4], w4[3];
#pragma unroll
        for (int i = 0; i < 4; ++i) e4[i] = *(const float4*)&e2L[(tx + 16 * i) * 100 + c4 * 4];
#pragma unroll
        for (int r = 0; r < 3; ++r) w4[r] = *(const float4*)&WL[(ty * 3 + r) * 100 + c4 * 4];
#pragma unroll
        for (int i = 0; i < 4; ++i)
#pragma unroll
            for (int r = 0; r < 3; ++r) {
                accv[i][r] = fmaf(e4[i].x, w4[r].x, accv[i][r]);
                accv[i][r] = fmaf(e4[i].y, w4[r].y, accv[i][r]);
                accv[i][r] = fmaf(e4[i].z, w4[r].z, accv[i][r]);
                accv[i][r] = fmaf(e4[i].w, w4[r].w, accv[i][r]);
            }
    }
    float al = a[0];
    float psum[4] = {};
#pragma unroll
    for (int r = 0; r < 3; ++r) {
        int co = ty * 3 + r;
        float sc = g[co] * rsqrtf(v[co] + 1e-5f);
        float fw = fcw[co], bi = sdb[co], mm = m[co], be = bb[co];
#pragma unroll
        for (int i = 0; i < 4; ++i) {
            float y = (accv[i][r] + bi - mm) * sc + be;
            y = y >= 0.f ? y : al * y;
            psum[i] = fmaf(fw, y, psum[i]);
        }
    }
#pragma unroll
    for (int i = 0; i < 4; ++i) red[(i * 16 + tx) * 17 + ty] = psum[i];
    __syncthreads();
    if (tid < 64) {
        float s = fcb[0];
#pragma unroll
        for (int y2 = 0; y2 < 16; ++y2) s += red[tid * 17 + y2];
        out[((size_t)b * 24 + h) * 1024 + t0 + tid] = s;
    }
}

// ---------- launch ----------
extern "C" void kernel_launch(void* const* d_in, const int* in_sizes, int n_in,
                              void* d_out, int out_size, void* d_ws, size_t ws_size,
                              hipStream_t stream)
{
    (void)in_sizes; (void)n_in; (void)out_size; (void)ws_size;
    const float* x        = (const float*)d_in[0];
    const float* eps      = (const float*)d_in[1];
    const float* sconv_w  = (const float*)d_in[2];
    const float* sconv_b  = (const float*)d_in[3];
    const float* tconv1_w = (const float*)d_in[4];
    const float* tconv1_b = (const float*)d_in[5];
    const float* tconv2_w = (const float*)d_in[6];
    const float* tconv2_b = (const float*)d_in[7];
    const float *bn1g=(const float*)d_in[8],  *bn1b=(const float*)d_in[9],  *bn1m=(const float*)d_in[10], *bn1v=(const float*)d_in[11], *a1=(const float*)d_in[12];
    const float *bn2g=(const float*)d_in[13], *bn2b=(const float*)d_in[14], *bn2m=(const float*)d_in[15], *bn2v=(const float*)d_in[16], *a2=(const float*)d_in[17];
    const float *bn3g=(const float*)d_in[18], *bn3b=(const float*)d_in[19], *bn3m=(const float*)d_in[20], *bn3v=(const float*)d_in[21], *a3=(const float*)d_in[22];
    const float *bn4g=(const float*)d_in[23], *bn4b=(const float*)d_in[24], *bn4m=(const float*)d_in[25], *bn4v=(const float*)d_in[26], *a4=(const float*)d_in[27];
    const float *bn5g=(const float*)d_in[28], *bn5b=(const float*)d_in[29], *bn5m=(const float*)d_in[30], *bn5v=(const float*)d_in[31], *a5=(const float*)d_in[32];
    const float *bn6g=(const float*)d_in[33], *bn6b=(const float*)d_in[34], *bn6m=(const float*)d_in[35], *bn6v=(const float*)d_in[36], *a6=(const float*)d_in[37];
    const float *wihf=(const float*)d_in[38], *whhf=(const float*)d_in[39], *bihf=(const float*)d_in[40], *bhhf=(const float*)d_in[41];
    const float *wihb=(const float*)d_in[42], *whhb=(const float*)d_in[43], *bihb=(const float*)d_in[44], *bhhb=(const float*)d_in[45];
    const float *mu_w=(const float*)d_in[46], *mu_b=(const float*)d_in[47];
    const float *lv_w=(const float*)d_in[48], *lv_b=(const float*)d_in[49];
    const float *dec_w=(const float*)d_in[50], *dec_b=(const float*)d_in[51];
    const float *dconv1_w=(const float*)d_in[52], *dconv1_b=(const float*)d_in[53];
    const float *dconv2_w=(const float*)d_in[54], *dconv2_b=(const float*)d_in[55];
    const float *sdconv_w=(const float*)d_in[56], *sdconv_b=(const float*)d_in[57];
    const float *fconv_w=(const float*)d_in[58], *fconv_b=(const float*)d_in[59];

    float* ws = (float*)d_ws;
    float* x1   = ws + 0;
    float* x2   = ws + 1572864;
    float* e0   = ws + 3145728;       // [B][384][256]; ch 192.. written by tconv2
    float* x3s  = ws + 6291456;       // [8192][192]  (dead after gemms)
    float* htmp = ws + 6291456;       // overlay on x3s: [2][256][32][96]
    float* wihT = ws + 7864320;       // [2][192][768]
    uint32_t* wfrag = (uint32_t*)(ws + 8159232);  // [2][12][4][6][64][4] u32 (bf16 B-frags)
    float* bsum = ws + 8306688;       // [2][768]
    float* gx   = ws + 8308736;       // [2][256][32][768]  (dead after lstm)
    float* z    = ws + 8308736;       // overlay on gx
    float* x4   = ws + 8603648;       // overlay on gx
    float* u1   = ws + 11749376;      // overlay on gx
    float* u2   = ws + 13322240;      // overlay on gx
    float* wsdT = ws + 20891648;      // [24][48][96]

    float* out0 = (float*)d_out;
    float* muo  = out0 + 786432;
    float* lvo  = muo + 294912;

    k_prep<<<1014, 256, 0, stream>>>(whhf, whhb, bihf, bhhf, bihb, bhhb,
                                     sdconv_w, wfrag, bsum, wsdT);
    k_prepT<<<dim3(3, 12, 2), 256, 0, stream>>>(wihf, wihb, wihT);
    k_sconv<<<dim3(4, 48, 32), 256, 0, stream>>>(x, sconv_w, sconv_b, bn1g, bn1b, bn1m, bn1v, a1, x1);
    k_tconv<48, 96, 512, 96><<<dim3(8, 6, 32), 256, 0, stream>>>(
        x1, tconv1_w, tconv1_b, bn2g, bn2b, bn2m, bn2v, a2, x2);
    k_tconv<96, 192, 256, 384><<<dim3(4, 12, 32), 256, 0, stream>>>(
        x2, tconv2_w, tconv2_b, bn3g, bn3b, bn3m, bn3v, a3, e0 + 49152);
    k_x3s<<<dim3(4, 32), 256, 0, stream>>>(e0, x3s);
    k_gemm<<<dim3(12, 128), 256, 0, stream>>>(x3s, wihT, bsum, gx);
    k_gemm<<<dim3(12, 128), 256, 0, stream>>>(x3s, wihT + 147456, bsum + 768, gx + 6291456);
    k_lstm_mfma<<<4, 768, 0, stream>>>(gx, (const short*)wfrag, htmp);
    k_hT<<<dim3(4, 32, 2), 256, 0, stream>>>(htmp, e0);
    k_muz<<<384, 256, 0, stream>>>(e0, mu_w, mu_b, lv_w, lv_b, eps, muo, lvo, z);
    k_dec<<<384, 256, 0, stream>>>(z, dec_w, dec_b, x4);
    k_convT<384, 48, 256, 384, 96><<<dim3(8, 2, 32), 256, 0, stream>>>(
        x4, x4, dconv1_w, dconv1_b, bn4g, bn4b, bn4m, bn4v, a4, u1);
    k_convT<192, 48, 512, 96, 48><<<dim3(16, 1, 32), 256, 0, stream>>>(
        u1, x2, dconv2_w, dconv2_b, bn5g, bn5b, bn5m, bn5v, a5, u2);
    k_final<<<dim3(16, 24, 32), 256, 0, stream>>>(
        u2, x1, wsdT, sdconv_b, bn6g, bn6b, bn6m, bn6v, a6, fconv_w, fconv_b, out0);
}